// Round 3
// baseline (453.495 us; speedup 1.0000x reference)
//
#include <hip/hip_runtime.h>
#include <cstdint>

#define EPS 1e-6f

constexpr int Bsz = 4, Hn = 16, Lseq = 8192, Dd = 64;
constexpr int BH = Bsz * Hn;              // 64
constexpr int CHUNK = 64;                 // rows per wave-chunk (was 128)
constexpr int CPB = Lseq / CHUNK;         // 128 chunks per (b,h)
constexpr int NCHUNKS = BH * CPB;         // 8192 waves -> 32 waves/CU possible
constexpr int WPB = 4;                    // waves per block
constexpr int R = 4;                      // rows per row-group per sub-chunk
constexpr int SUB = 4 * R;                // 16 rows per sub-chunk

// native clang vector for nontemporal builtins (HIP_vector_type is rejected)
typedef float vfloat4 __attribute__((ext_vector_type(4)));

// feature map: x>0 ? x+1 : exp(x). __expf -> v_exp_f32 (cheap, ~1 ULP)
__device__ __forceinline__ float phi(float x) {
    return x > 0.0f ? x + 1.0f : __expf(x);
}

// ---------------- kernel 1: per-chunk aggregates (order-free) ----------------
// v3: latency fix — unroll x4 with an explicit load block (12 vmem ops in
// flight per wave instead of 3) + 2x wave count via CHUNK=64.
__global__ __launch_bounds__(256) void partials_kernel(
    const float* __restrict__ k, const float* __restrict__ v,
    const float* __restrict__ mask,
    float* __restrict__ pk, float* __restrict__ pkv)
{
    const int wave = blockIdx.x * WPB + (threadIdx.x >> 6);
    const int lane = threadIdx.x & 63;
    const int rg = lane >> 4;          // row group 0..3
    const int dg = lane & 15;          // dim group: dims [4*dg, 4*dg+4)
    const int bh = wave / CPB;
    const int c  = wave % CPB;
    const int b  = bh / Hn;
    const int l0 = c * CHUNK;

    float4 ak  = make_float4(0.f, 0.f, 0.f, 0.f);
    float4 akv = make_float4(0.f, 0.f, 0.f, 0.f);

    for (int i = 0; i < CHUNK; i += 16) {
        float4 k4[4], v4[4];
        float  m[4];
        // load block: 8 float4 + 4 scalar loads issued back-to-back
        #pragma unroll
        for (int u = 0; u < 4; ++u) {
            const int l = l0 + i + 4 * u + rg;
            const size_t off = ((size_t)bh * Lseq + l) * Dd + dg * 4;
            k4[u] = *(const float4*)(k + off);
            v4[u] = *(const float4*)(v + off);
            m[u]  = mask[(size_t)b * Lseq + l];
        }
        // compute block
        #pragma unroll
        for (int u = 0; u < 4; ++u) {
            float t;
            t = phi(k4[u].x) * m[u]; ak.x += t; akv.x += t * (v4[u].x * m[u]);
            t = phi(k4[u].y) * m[u]; ak.y += t; akv.y += t * (v4[u].y * m[u]);
            t = phi(k4[u].z) * m[u]; ak.z += t; akv.z += t * (v4[u].z * m[u]);
            t = phi(k4[u].w) * m[u]; ak.w += t; akv.w += t * (v4[u].w * m[u]);
        }
    }

    // reduce across the 4 row groups (xor 16, 32) — butterfly: all lanes get total
    #pragma unroll
    for (int off = 16; off <= 32; off <<= 1) {
        ak.x  += __shfl_xor(ak.x,  off, 64);
        ak.y  += __shfl_xor(ak.y,  off, 64);
        ak.z  += __shfl_xor(ak.z,  off, 64);
        ak.w  += __shfl_xor(ak.w,  off, 64);
        akv.x += __shfl_xor(akv.x, off, 64);
        akv.y += __shfl_xor(akv.y, off, 64);
        akv.z += __shfl_xor(akv.z, off, 64);
        akv.w += __shfl_xor(akv.w, off, 64);
    }

    if (rg == 0) {
        const size_t o = (size_t)wave * Dd + dg * 4;
        *(float4*)(pk  + o) = ak;
        *(float4*)(pkv + o) = akv;
    }
}

// ------------- kernel 2: exclusive scan over chunk aggregates ----------------
// CPB=128: one wave per (bh, d), 2 consecutive chunks per lane.
__global__ __launch_bounds__(256) void scan_kernel(
    float* __restrict__ pk, float* __restrict__ pkv)
{
    const int w    = blockIdx.x * 4 + (threadIdx.x >> 6);  // (bh,d) id, 0..4095
    const int lane = threadIdx.x & 63;
    const int bh   = w >> 6;
    const int d    = w & 63;
    const int c0   = lane * 2;
    const size_t o0 = ((size_t)(bh * CPB + c0)) * Dd + d;
    const size_t o1 = o0 + Dd;

    const float tk0  = pk[o0],  tk1  = pk[o1];
    const float tkv0 = pkv[o0], tkv1 = pkv[o1];
    const float sk  = tk0 + tk1;
    const float skv = tkv0 + tkv1;

    float ik = sk, ikv = skv;
    #pragma unroll
    for (int off = 1; off <= 32; off <<= 1) {
        const float t1 = __shfl_up(ik,  off, 64);
        const float t2 = __shfl_up(ikv, off, 64);
        if (lane >= off) { ik += t1; ikv += t2; }
    }
    const float ek  = ik  - sk;   // exclusive prefix at c0
    const float ekv = ikv - skv;
    pk[o0]  = ek;          pkv[o0] = ekv;
    pk[o1]  = ek + tk0;    pkv[o1] = ekv + tkv0;
}

// ---------------- kernel 3: final pass with exact inclusive prefix -----------
// v3: q-loads hoisted into the k/v load block (12 vmem in flight), CHUNK=64.
__global__ __launch_bounds__(256) void final_kernel(
    const float* __restrict__ q, const float* __restrict__ k,
    const float* __restrict__ v, const float* __restrict__ mask,
    const float* __restrict__ pk, const float* __restrict__ pkv,
    float* __restrict__ out)
{
    const int wave = blockIdx.x * WPB + (threadIdx.x >> 6);
    const int lane = threadIdx.x & 63;
    const int rg = lane >> 4;
    const int dg = lane & 15;
    const int bh = wave / CPB;
    const int c  = wave % CPB;
    const int b  = bh / Hn;
    const int l0 = c * CHUNK;

    const size_t po = (size_t)wave * Dd + dg * 4;
    float4 Sk  = *(const float4*)(pk  + po);   // exclusive prefix for this chunk
    float4 Skv = *(const float4*)(pkv + po);

    for (int s = 0; s < CHUNK / SUB; ++s) {
        const int lbase = l0 + s * SUB + rg * R;  // blocked row assignment

        float4 k4[R], v4[R], q4[R];
        float  ms[R];
        // load block: 12 float4 + 4 scalar loads in flight
        #pragma unroll
        for (int j = 0; j < R; ++j) {
            const int l = lbase + j;
            const size_t off = ((size_t)bh * Lseq + l) * Dd + dg * 4;
            k4[j] = *(const float4*)(k + off);
            v4[j] = *(const float4*)(v + off);
            q4[j] = *(const float4*)(q + off);
            ms[j] = mask[(size_t)b * Lseq + l];
        }

        float4 pa[R], pakv[R];
        float4 ra   = make_float4(0.f, 0.f, 0.f, 0.f);
        float4 rakv = make_float4(0.f, 0.f, 0.f, 0.f);

        // sequential local inclusive prefix over this rg's R rows
        #pragma unroll
        for (int j = 0; j < R; ++j) {
            const float m = ms[j];
            float t;
            t = phi(k4[j].x) * m; ra.x += t; rakv.x += t * (v4[j].x * m);
            t = phi(k4[j].y) * m; ra.y += t; rakv.y += t * (v4[j].y * m);
            t = phi(k4[j].z) * m; ra.z += t; rakv.z += t * (v4[j].z * m);
            t = phi(k4[j].w) * m; ra.w += t; rakv.w += t * (v4[j].w * m);
            pa[j]   = ra;
            pakv[j] = rakv;
        }

        // Inclusive scan of sub-block totals across the 4 row groups
        float4 ia = ra, iakv = rakv;
        float t;
        t = __shfl_up(ia.x,   16, 64); if (rg >= 1) ia.x   += t;
        t = __shfl_up(ia.y,   16, 64); if (rg >= 1) ia.y   += t;
        t = __shfl_up(ia.z,   16, 64); if (rg >= 1) ia.z   += t;
        t = __shfl_up(ia.w,   16, 64); if (rg >= 1) ia.w   += t;
        t = __shfl_up(iakv.x, 16, 64); if (rg >= 1) iakv.x += t;
        t = __shfl_up(iakv.y, 16, 64); if (rg >= 1) iakv.y += t;
        t = __shfl_up(iakv.z, 16, 64); if (rg >= 1) iakv.z += t;
        t = __shfl_up(iakv.w, 16, 64); if (rg >= 1) iakv.w += t;
        t = __shfl_up(ia.x,   32, 64); if (rg >= 2) ia.x   += t;
        t = __shfl_up(ia.y,   32, 64); if (rg >= 2) ia.y   += t;
        t = __shfl_up(ia.z,   32, 64); if (rg >= 2) ia.z   += t;
        t = __shfl_up(ia.w,   32, 64); if (rg >= 2) ia.w   += t;
        t = __shfl_up(iakv.x, 32, 64); if (rg >= 2) iakv.x += t;
        t = __shfl_up(iakv.y, 32, 64); if (rg >= 2) iakv.y += t;
        t = __shfl_up(iakv.z, 32, 64); if (rg >= 2) iakv.z += t;
        t = __shfl_up(iakv.w, 32, 64); if (rg >= 2) iakv.w += t;

        // exclusive offset for this rg = chunk prefix + (inclusive - own total)
        const float4 ofk = make_float4(Sk.x + ia.x - ra.x, Sk.y + ia.y - ra.y,
                                       Sk.z + ia.z - ra.z, Sk.w + ia.w - ra.w);
        const float4 ofkv = make_float4(Skv.x + iakv.x - rakv.x, Skv.y + iakv.y - rakv.y,
                                        Skv.z + iakv.z - rakv.z, Skv.w + iakv.w - rakv.w);

        // advance chunk prefix by the whole sub-chunk total (inclusive at rg==3)
        Sk.x  += __shfl(ia.x,   48 + dg, 64);
        Sk.y  += __shfl(ia.y,   48 + dg, 64);
        Sk.z  += __shfl(ia.z,   48 + dg, 64);
        Sk.w  += __shfl(ia.w,   48 + dg, 64);
        Skv.x += __shfl(iakv.x, 48 + dg, 64);
        Skv.y += __shfl(iakv.y, 48 + dg, 64);
        Skv.z += __shfl(iakv.z, 48 + dg, 64);
        Skv.w += __shfl(iakv.w, 48 + dg, 64);

        // produce output for this rg's R rows
        #pragma unroll
        for (int j = 0; j < R; ++j) {
            const int l = lbase + j;
            const size_t off = ((size_t)bh * Lseq + l) * Dd + dg * 4;
            const float m = ms[j];

            float4 fq;
            fq.x = phi(q4[j].x); fq.y = phi(q4[j].y);
            fq.z = phi(q4[j].z); fq.w = phi(q4[j].w);

            const float4 ik  = make_float4(ofk.x  + pa[j].x,   ofk.y  + pa[j].y,
                                           ofk.z  + pa[j].z,   ofk.w  + pa[j].w);
            const float4 ikv = make_float4(ofkv.x + pakv[j].x, ofkv.y + pakv[j].y,
                                           ofkv.z + pakv[j].z, ofkv.w + pakv[j].w);

            // z = (sum_d phi(q)*k_cumsum + EPS) * mask  (reduce over 16 dg lanes)
            float p = fq.x * ik.x + fq.y * ik.y + fq.z * ik.z + fq.w * ik.w;
            p += __shfl_xor(p, 1, 64);
            p += __shfl_xor(p, 2, 64);
            p += __shfl_xor(p, 4, 64);
            p += __shfl_xor(p, 8, 64);
            const float z = (p + EPS) * m;
            const float inv = 1.0f / z;

            vfloat4 o4;
            o4.x = fq.x * ikv.x * inv;
            o4.y = fq.y * ikv.y * inv;
            o4.z = fq.z * ikv.z * inv;
            o4.w = fq.w * ikv.w * inv;
            // out is never re-read: nontemporal store keeps q/k/v lines cached
            __builtin_nontemporal_store(o4, (vfloat4*)(out + off));
        }
    }
}

extern "C" void kernel_launch(void* const* d_in, const int* in_sizes, int n_in,
                              void* d_out, int out_size, void* d_ws, size_t ws_size,
                              hipStream_t stream) {
    const float* q    = (const float*)d_in[0];
    const float* k    = (const float*)d_in[1];
    const float* v    = (const float*)d_in[2];
    const float* mask = (const float*)d_in[3];
    float* out = (float*)d_out;

    // workspace: 2 arrays of NCHUNKS*64 floats = 4 MiB total
    float* pk  = (float*)d_ws;
    float* pkv = pk + (size_t)NCHUNKS * Dd;

    partials_kernel<<<NCHUNKS / WPB, 256, 0, stream>>>(k, v, mask, pk, pkv);
    scan_kernel<<<(BH * Dd) / 4, 256, 0, stream>>>(pk, pkv);
    final_kernel<<<NCHUNKS / WPB, 256, 0, stream>>>(q, k, v, mask, pk, pkv, out);
}